// Round 19
// baseline (122.284 us; speedup 1.0000x reference)
//
#include <hip/hip_runtime.h>
#include <hip/hip_fp16.h>

#define NN 50000
#define NE 800000
#define NG 512
#define DD 128
#define NSB 64               // sub-bins == subpartitions
#define SUBN 782             // ceil(NN/NSB)
#define SBCAP 14336          // per-sub-bin capacity
#define NB1 512
#define NI4 (NE / 4)
#define CH4 ((NI4 + NB1 - 1) / NB1)
#define F2HB 6250            // f2h blocks: NN*32/256

typedef __attribute__((ext_vector_type(8))) _Float16 f16x8;
typedef __attribute__((ext_vector_type(4))) float f32x4;
typedef int v4i __attribute__((ext_vector_type(4)));

// ---- zero the bin cursors (replaces two hipMemsetAsync graph nodes) ----
__global__ void k_zero(int* __restrict__ p) {
  p[threadIdx.x] = 0;   // 128 ints: cur_d[64] + cur_s[64] (contiguous)
}

// ---- merged prep: b<8 W1-split | b==8 W2c | 9<=b<521 edge binning | b>=521 f2h ----
__global__ __launch_bounds__(256) void k_prep(
    const float* __restrict__ W1, const float* __restrict__ W2,
    const float* __restrict__ Wc, const float* __restrict__ b2,
    const float* __restrict__ bc,
    _Float16* __restrict__ w1hi, _Float16* __restrict__ w1lo,
    float* __restrict__ w2c, float* __restrict__ zc,
    const int* __restrict__ src, const int* __restrict__ dst,
    int* __restrict__ cur_d, int* __restrict__ cur_s,
    unsigned long long* __restrict__ byDst, unsigned short* __restrict__ bySrc,
    const float4* __restrict__ x, uint2* __restrict__ xh) {
  __shared__ int cntd[4][NSB], cnts[4][NSB], based[NSB], bases[NSB];
  __shared__ int wbd[4][NSB], wbs[4][NSB];
  int b = blockIdx.x;
  int tid = threadIdx.x;
  if (b >= 521) {
    // f2h: features f32 -> fp16 (UNscaled; out_norm applied in k_agg)
    int i = (b - 521) * 256 + tid;      // < NN*32
    float4 v = x[i];
    __half2 a = __floats2half2_rn(v.x, v.y);
    __half2 c = __floats2half2_rn(v.z, v.w);
    uint2 o;
    o.x = *(unsigned int*)&a;
    o.y = *(unsigned int*)&c;
    xh[i] = o;
  } else if (b < 8) {
    // W1 split into MFMA B-fragment order
    int t = b * 256 + tid;
    int lane = t & 63;
    int grp = t >> 6;
    int kk = grp & 3;
    int nt = grp >> 2;
    int kbase = kk * 32 + ((lane >> 4) << 3);
    int c = nt * 16 + (lane & 15);
#pragma unroll
    for (int j = 0; j < 8; ++j) {
      float v = W1[(kbase + j) * DD + c];
      _Float16 h = (_Float16)v;
      w1hi[t * 8 + j] = h;
      w1lo[t * 8 + j] = (_Float16)(v - (float)h);
    }
  } else if (b == 8) {
    // W2c = W2 @ Wc [128][2]; zc = b2 @ Wc + bc [2]
    int row = tid >> 1, cc = tid & 1;
    float s = 0.f;
#pragma unroll 8
    for (int c = 0; c < DD; ++c) s += W2[row * DD + c] * Wc[c * 2 + cc];
    w2c[row * 2 + cc] = s;
    if (tid < 2) {
      float bb = 0.f;
      for (int c = 0; c < DD; ++c) bb += b2[c] * Wc[c * 2 + tid];
      zc[tid] = bb + bc[tid];
    }
  } else {
    // edge binning (chunk b-9), 4-way wave-privatized LDS histograms
    int w = tid >> 6;
    int i0 = (b - 9) * CH4;
    int i1 = i0 + CH4; if (i1 > NI4) i1 = NI4;
    if (tid < NSB) {
#pragma unroll
      for (int ww = 0; ww < 4; ++ww) { cntd[ww][tid] = 0; cnts[ww][tid] = 0; }
    }
    __syncthreads();
    const v4i* s4 = (const v4i*)src;
    const v4i* d4 = (const v4i*)dst;
    for (int i = i0 + tid; i < i1; i += 256) {
      v4i sv = __builtin_nontemporal_load(&s4[i]);
      v4i dv = __builtin_nontemporal_load(&d4[i]);
#pragma unroll
      for (int k = 0; k < 4; ++k) {
        atomicAdd(&cntd[w][dv[k] / SUBN], 1);
        atomicAdd(&cnts[w][sv[k] / SUBN], 1);
      }
    }
    __syncthreads();
    if (tid < NSB) {
      int run = 0;
#pragma unroll
      for (int ww = 0; ww < 4; ++ww) { wbd[ww][tid] = run; run += cntd[ww][tid]; }
      based[tid] = atomicAdd(&cur_d[tid], run);
#pragma unroll
      for (int ww = 0; ww < 4; ++ww) cntd[ww][tid] = 0;
    } else if (tid < 2 * NSB) {
      int q = tid - NSB;
      int run = 0;
#pragma unroll
      for (int ww = 0; ww < 4; ++ww) { wbs[ww][q] = run; run += cnts[ww][q]; }
      bases[q] = atomicAdd(&cur_s[q], run);
#pragma unroll
      for (int ww = 0; ww < 4; ++ww) cnts[ww][q] = 0;
    }
    __syncthreads();
    for (int i = i0 + tid; i < i1; i += 256) {
      v4i sv = __builtin_nontemporal_load(&s4[i]);
      v4i dv = __builtin_nontemporal_load(&d4[i]);
#pragma unroll
      for (int k = 0; k < 4; ++k) {
        int d = dv[k], s = sv[k];
        int bd = d / SUBN;
        int pd = based[bd] + wbd[w][bd] + atomicAdd(&cntd[w][bd], 1);
        if (pd < SBCAP) byDst[(size_t)bd * SBCAP + pd] = ((unsigned long long)(unsigned)d << 32) | (unsigned)s;
        int bs = s / SUBN;
        int ps = bases[bs] + wbs[w][bs] + atomicAdd(&cnts[w][bs], 1);
        if (ps < SBCAP) bySrc[(size_t)bs * SBCAP + ps] = (unsigned short)(s - bs * SUBN);
      }
    }
  }
}

// ---- merged P2: blocks 0-63 dst-side (CSR + deg_in + in_norm),
//                 blocks 64-127 src-side (out_norm). No global atomics. ----
__global__ __launch_bounds__(1024) void k_csr2(
    const unsigned long long* __restrict__ byDst, const int* __restrict__ cur_d,
    const unsigned short* __restrict__ bySrc, const int* __restrict__ cur_s,
    int* __restrict__ csr, int* __restrict__ row_start, int* __restrict__ deg_in,
    float* __restrict__ in_norm, float* __restrict__ out_norm) {
  __shared__ int hist[SUBN];
  __shared__ int wsum[16];
  int b = blockIdx.x;
  int tid = threadIdx.x;
  if (b < 64) {
    int q = b;
    int nlo = q * SUBN;
    int nhi = nlo + SUBN; if (nhi > NN) nhi = NN;
    int nloc = nhi - nlo;
    for (int i = tid; i < SUBN; i += 1024) hist[i] = 0;
    __syncthreads();
    int m = cur_d[q];
    if (m > SBCAP) m = SBCAP;
    const unsigned long long* bine = byDst + (size_t)q * SBCAP;
    for (int i = tid; i < m; i += 1024) {
      int l = (int)(bine[i] >> 32) - nlo;
      if (l >= 0 && l < nloc) atomicAdd(&hist[l], 1);
    }
    __syncthreads();
    int v = (tid < SUBN) ? hist[tid] : 0;
    int incl = v;
    int lane = tid & 63;
#pragma unroll
    for (int off = 1; off < 64; off <<= 1) {
      int t2 = __shfl_up(incl, off);
      if (lane >= off) incl += t2;
    }
    int wid = tid >> 6;
    if (lane == 63) wsum[wid] = incl;
    __syncthreads();
    if (tid == 0) {
      int run = 0;
      for (int i = 0; i < 16; ++i) { int t = wsum[i]; wsum[i] = run; run += t; }
    }
    __syncthreads();
    int excl = incl - v + wsum[wid];
    if (tid < nloc) {
      deg_in[nlo + tid] = v;
      row_start[nlo + tid] = q * SBCAP + excl;
      in_norm[nlo + tid] = v > 0 ? rsqrtf((float)v) : 0.f;
    }
    __syncthreads();
    if (tid < SUBN) hist[tid] = excl;   // scatter cursor
    __syncthreads();
    for (int i = tid; i < m; i += 1024) {
      unsigned long long p = bine[i];
      int l = (int)(p >> 32) - nlo;
      if (l >= 0 && l < nloc) {
        int pos = atomicAdd(&hist[l], 1);
        if (pos < SBCAP) csr[(size_t)q * SBCAP + pos] = (int)(unsigned)p;
      }
    }
  } else {
    int q = b - 64;
    int nlo = q * SUBN;
    int nhi = nlo + SUBN; if (nhi > NN) nhi = NN;
    int nloc = nhi - nlo;
    for (int i = tid; i < SUBN; i += 1024) hist[i] = 0;
    __syncthreads();
    int m = cur_s[q];
    if (m > SBCAP) m = SBCAP;
    const unsigned short* bine = bySrc + (size_t)q * SBCAP;
    for (int i = tid; i < m; i += 1024) {
      atomicAdd(&hist[bine[i]], 1);
    }
    __syncthreads();
    for (int i = tid; i < nloc; i += 1024) {
      int od = hist[i];
      out_norm[nlo + i] = od > 0 ? rsqrtf((float)od) : 0.f;
    }
  }
}

// ---- aggregation (layer 1): one wave per dst node. TWO rows per gather
// instruction: lanes 0-31 handle even edges, 32-63 odd edges; each lane loads
// 8 B (4 cols) of its row. 8-deep unroll -> 16 rows in flight per wave.
// Final shfl_xor(32) merges even/odd partials; lanes 0-31 store fp16 row. ----
__global__ __launch_bounds__(256) void k_agg(
    const __half* __restrict__ x, const int* __restrict__ csr,
    const int* __restrict__ row_start, const int* __restrict__ deg_in,
    const float* __restrict__ out_norm, uint2* __restrict__ agg) {
  int node = blockIdx.x * 4 + (threadIdx.x >> 6);
  int lane = threadIdx.x & 63;
  if (node >= NN) return;
  int n = deg_in[node];
  const int* bk = csr + row_start[node];
  const uint2* xv = (const uint2*)x;        // 8 B slots; row = 32 slots
  int half_ = lane >> 5;                    // 0: even edges, 1: odd edges
  int l32 = lane & 31;                      // slot within row
  float4 acc[8];
#pragma unroll
  for (int u = 0; u < 8; ++u) acc[u] = make_float4(0.f, 0.f, 0.f, 0.f);
  for (int c0 = 0; c0 < n; c0 += 64) {
    int nn = n - c0; if (nn > 64) nn = 64;
    int sl = 0; float wl = 0.f;
    if (lane < nn) { sl = bk[c0 + lane]; wl = out_norm[sl]; }
    for (int j = 0; j < nn; j += 16) {
#pragma unroll
      for (int u = 0; u < 8; ++u) {
        int e = j + 2 * u + half_;
        int s = __shfl(sl, e);
        float w = __shfl(wl, e);
        if (e < nn) {
          uint2 raw = xv[(size_t)s * 32 + l32];
          float2 f0 = __half22float2(*(__half2*)&raw.x);
          float2 f1 = __half22float2(*(__half2*)&raw.y);
          acc[u].x += f0.x * w; acc[u].y += f0.y * w;
          acc[u].z += f1.x * w; acc[u].w += f1.y * w;
        }
      }
    }
  }
  float4 a = acc[0];
#pragma unroll
  for (int u = 1; u < 8; ++u) {
    a.x += acc[u].x; a.y += acc[u].y; a.z += acc[u].z; a.w += acc[u].w;
  }
  a.x += __shfl_xor(a.x, 32);
  a.y += __shfl_xor(a.y, 32);
  a.z += __shfl_xor(a.z, 32);
  a.w += __shfl_xor(a.w, 32);
  if (lane < 32) {
    __half2 h0 = __floats2half2_rn(a.x, a.y);
    __half2 h1 = __floats2half2_rn(a.z, a.w);
    uint2 o;
    o.x = *(unsigned int*)&h0;
    o.y = *(unsigned int*)&h1;
    agg[(size_t)node * 32 + l32] = o;
  }
}

// ---- layer-1 MFMA GEMM + fused layer-2 projection ----
// A fp16; W split keeps W precision: acc = A·W_hi + A·W_lo.
// h1 = relu(in_norm*(A@W1) + b1) in registers; p[row] = out_norm*(h1@W2c).
__global__ __launch_bounds__(256, 4) void k_gemm1(
    const __half* __restrict__ A, const float* __restrict__ in_norm,
    const float* __restrict__ out_norm,
    const _Float16* __restrict__ Whi, const _Float16* __restrict__ Wlo,
    const float* __restrict__ bias, const float* __restrict__ W2c,
    float2* __restrict__ p) {
  int tid = threadIdx.x;
  int wid = tid >> 6, lane = tid & 63;
  int row0 = blockIdx.x * 64 + wid * 16;
  int ar = row0 + (lane & 15);
  bool rv = ar < NN;
  f16x8 a_[4];
#pragma unroll
  for (int kk = 0; kk < 4; ++kk) {
    if (rv) {
      a_[kk] = *(const f16x8*)((const _Float16*)A + (size_t)ar * DD + kk * 32 + ((lane >> 4) << 3));
    } else {
      a_[kk] = (f16x8){0, 0, 0, 0, 0, 0, 0, 0};
    }
  }
  f32x4 acc[8];
#pragma unroll
  for (int nt = 0; nt < 8; ++nt) acc[nt] = (f32x4){0.f, 0.f, 0.f, 0.f};
#pragma unroll
  for (int nt = 0; nt < 8; ++nt) {
#pragma unroll
    for (int kk = 0; kk < 4; ++kk) {
      f16x8 bh = *(const f16x8*)&Whi[(((nt * 4 + kk) * 64) + lane) * 8];
      f16x8 bl = *(const f16x8*)&Wlo[(((nt * 4 + kk) * 64) + lane) * 8];
      acc[nt] = __builtin_amdgcn_mfma_f32_16x16x32_f16(a_[kk], bh, acc[nt], 0, 0, 0);
      acc[nt] = __builtin_amdgcn_mfma_f32_16x16x32_f16(a_[kk], bl, acc[nt], 0, 0, 0);
    }
  }
  int r4 = (lane >> 4) * 4;
  int c0 = lane & 15;
  float wc0[8], wc1[8], bv[8];
#pragma unroll
  for (int nt = 0; nt < 8; ++nt) {
    int col = nt * 16 + c0;
    wc0[nt] = W2c[col * 2 + 0];
    wc1[nt] = W2c[col * 2 + 1];
    bv[nt] = bias[col];
  }
#pragma unroll
  for (int reg = 0; reg < 4; ++reg) {
    int row = row0 + r4 + reg;
    float inm = (row < NN) ? in_norm[row] : 0.f;
    float v0 = 0.f, v1 = 0.f;
#pragma unroll
    for (int nt = 0; nt < 8; ++nt) {
      float y = acc[nt][reg] * inm + bv[nt];
      y = fmaxf(y, 0.f);
      v0 += y * wc0[nt];
      v1 += y * wc1[nt];
    }
#pragma unroll
    for (int off = 1; off < 16; off <<= 1) {
      v0 += __shfl_xor(v0, off);
      v1 += __shfl_xor(v1, off);
    }
    if (row < NN && c0 == 0) {
      float onm = out_norm[row];
      p[row] = make_float2(v0 * onm, v1 * onm);
    }
  }
}

// ---- layer-2 aggregation on 2-dim projections: z[i] = in_norm[i] * sum p[nbr] ----
__global__ __launch_bounds__(256) void k_agg2(
    const float2* __restrict__ p, const int* __restrict__ csr,
    const int* __restrict__ row_start, const int* __restrict__ deg_in,
    const float* __restrict__ in_norm, float2* __restrict__ z) {
  int i = blockIdx.x * 256 + threadIdx.x;
  if (i >= NN) return;
  int n = deg_in[i];
  const int* bk = csr + row_start[i];
  float2 s0 = {0.f, 0.f}, s1 = {0.f, 0.f}, s2 = {0.f, 0.f}, s3 = {0.f, 0.f};
  int j = 0;
  for (; j + 4 <= n; j += 4) {
    int i0 = bk[j], i1 = bk[j + 1], i2 = bk[j + 2], i3 = bk[j + 3];
    float2 q0 = p[i0], q1 = p[i1], q2 = p[i2], q3 = p[i3];
    s0.x += q0.x; s0.y += q0.y;
    s1.x += q1.x; s1.y += q1.y;
    s2.x += q2.x; s2.y += q2.y;
    s3.x += q3.x; s3.y += q3.y;
  }
  for (; j < n; ++j) {
    float2 q = p[bk[j]];
    s0.x += q.x; s0.y += q.y;
  }
  s0.x += s1.x + s2.x + s3.x;
  s0.y += s1.y + s2.y + s3.y;
  float inm = in_norm[i];
  z[i] = make_float2(s0.x * inm, s0.y * inm);
}

// ---- pool: one wave per graph; segment-mean of z + zc -> out ----
__global__ __launch_bounds__(256) void k_pool2(
    const float* __restrict__ z, const int* __restrict__ gid,
    const float* __restrict__ zc, float* __restrict__ out) {
  int g = blockIdx.x * 4 + (threadIdx.x >> 6);
  int lane = threadIdx.x & 63;
  if (g >= NG) return;
  int lo, hi;
  { int a = 0, b = NN; while (a < b) { int m = (a + b) >> 1; if (gid[m] < g) a = m + 1; else b = m; } lo = a; }
  { int a = lo, b = NN; while (a < b) { int m = (a + b) >> 1; if (gid[m] <= g) a = m + 1; else b = m; } hi = a; }
  float s = 0.f;
  int col = lane & 1;
  for (int i = lo + (lane >> 1); i < hi; i += 32) s += z[i * 2 + col];
#pragma unroll
  for (int off = 32; off >= 2; off >>= 1) s += __shfl_down(s, off);
  if (lane < 2) {
    int n = hi - lo;
    out[g * 2 + lane] = s / (float)(n > 0 ? n : 1) + zc[lane];
  }
}

extern "C" void kernel_launch(void* const* d_in, const int* in_sizes, int n_in,
                              void* d_out, int out_size, void* d_ws, size_t ws_size,
                              hipStream_t stream) {
  const float* features = (const float*)d_in[0];
  const int* src = (const int*)d_in[1];
  const int* dst = (const int*)d_in[2];
  const int* gid = (const int*)d_in[3];
  const float* W1 = (const float*)d_in[4];
  const float* b1 = (const float*)d_in[5];
  const float* W2 = (const float*)d_in[6];
  const float* b2 = (const float*)d_in[7];
  const float* Wc = (const float*)d_in[8];
  const float* bc = (const float*)d_in[9];
  float* out = (float*)d_out;

  char* ws = (char*)d_ws;
  size_t off = 0;
  auto take = [&](size_t bytes) {
    char* p = ws + off;
    off = (off + bytes + 255) & ~(size_t)255;
    return p;
  };
  int* cur_d      = (int*)take(NSB * 4);   // cur_d at +0, cur_s at +256 B
  int* cur_s      = (int*)take(NSB * 4);
  int* deg_in     = (int*)take((size_t)NN * 4);
  float* out_nrm  = (float*)take((size_t)NN * 4);
  float* in_nrm   = (float*)take((size_t)NN * 4);
  int* row_start  = (int*)take((size_t)NN * 4);
  float* pbuf     = (float*)take((size_t)NN * 2 * 4);
  float* zbuf     = (float*)take((size_t)NN * 2 * 4);
  float* w2c      = (float*)take((size_t)DD * 2 * 4);
  float* zc       = (float*)take(2 * 4);
  unsigned long long* byDst = (unsigned long long*)take((size_t)NSB * SBCAP * 8);
  unsigned short* bySrc = (unsigned short*)take((size_t)NSB * SBCAP * 2);
  int* csr        = (int*)take((size_t)NSB * SBCAP * 4);
  __half* xh      = (__half*)take((size_t)NN * DD * 2);
  __half* bufA    = (__half*)take((size_t)NN * DD * 2);
  _Float16* w1hi  = (_Float16*)take((size_t)DD * DD * 2);
  _Float16* w1lo  = (_Float16*)take((size_t)DD * DD * 2);

  // zero bin cursors
  k_zero<<<1, 128, 0, stream>>>(cur_d);

  // prep: W1 split + W2c + edge binning + f2h
  k_prep<<<521 + F2HB, 256, 0, stream>>>(
      W1, W2, Wc, b2, bc, w1hi, w1lo, w2c, zc,
      src, dst, cur_d, cur_s, byDst, bySrc,
      (const float4*)features, (uint2*)xh);

  // CSR build + degrees + norms
  k_csr2<<<128, 1024, 0, stream>>>(
      byDst, cur_d, bySrc, cur_s, csr, row_start, deg_in, in_nrm, out_nrm);

  // layer 1: agg (2-rows-per-instruction, fp16 out) -> bufA ; GEMM + projection -> pbuf
  k_agg<<<(NN + 3) / 4, 256, 0, stream>>>(
      xh, csr, row_start, deg_in, out_nrm, (uint2*)bufA);
  k_gemm1<<<(NN + 63) / 64, 256, 0, stream>>>(
      bufA, in_nrm, out_nrm, w1hi, w1lo, b1, w2c, (float2*)pbuf);

  // layer 2 (algebraically reduced): 2-dim aggregate + norm -> zbuf
  k_agg2<<<(NN + 255) / 256, 256, 0, stream>>>(
      (const float2*)pbuf, csr, row_start, deg_in, in_nrm, (float2*)zbuf);

  // segment mean-pool (+ b2@Wc + bc)
  k_pool2<<<(NG + 3) / 4, 256, 0, stream>>>(zbuf, gid, zc, out);
}

// Round 20
// 110.519 us; speedup vs baseline: 1.1065x; 1.1065x over previous
//
#include <hip/hip_runtime.h>
#include <hip/hip_fp16.h>

#define NN 50000
#define NE 800000
#define NG 512
#define DD 128
#define NSB 64               // sub-bins == subpartitions
#define SUBN 782             // ceil(NN/NSB)
#define SBCAP 14336          // per-sub-bin capacity
#define NB1 512
#define NI4 (NE / 4)
#define CH4 ((NI4 + NB1 - 1) / NB1)
#define F2HB 6250            // f2h blocks: NN*32/256

typedef __attribute__((ext_vector_type(8))) _Float16 f16x8;
typedef __attribute__((ext_vector_type(4))) float f32x4;
typedef int v4i __attribute__((ext_vector_type(4)));

// ---- zero the bin cursors ----
__global__ void k_zero(int* __restrict__ p) {
  p[threadIdx.x] = 0;   // 128 ints: cur_d[64] + cur_s[64]
}

// ---- merged prep: b<8 W1-split | b==8 W2c | 9<=b<521 edge binning | b>=521 f2h ----
__global__ __launch_bounds__(256) void k_prep(
    const float* __restrict__ W1, const float* __restrict__ W2,
    const float* __restrict__ Wc, const float* __restrict__ b2,
    const float* __restrict__ bc,
    _Float16* __restrict__ w1hi, _Float16* __restrict__ w1lo,
    float* __restrict__ w2c, float* __restrict__ zc,
    const int* __restrict__ src, const int* __restrict__ dst,
    int* __restrict__ cur_d, int* __restrict__ cur_s,
    unsigned long long* __restrict__ byDst, unsigned short* __restrict__ bySrc,
    const float4* __restrict__ x, uint2* __restrict__ xh) {
  __shared__ int cntd[4][NSB], cnts[4][NSB], based[NSB], bases[NSB];
  __shared__ int wbd[4][NSB], wbs[4][NSB];
  int b = blockIdx.x;
  int tid = threadIdx.x;
  if (b >= 521) {
    int i = (b - 521) * 256 + tid;      // < NN*32
    float4 v = x[i];
    __half2 a = __floats2half2_rn(v.x, v.y);
    __half2 c = __floats2half2_rn(v.z, v.w);
    uint2 o;
    o.x = *(unsigned int*)&a;
    o.y = *(unsigned int*)&c;
    xh[i] = o;
  } else if (b < 8) {
    int t = b * 256 + tid;
    int lane = t & 63;
    int grp = t >> 6;
    int kk = grp & 3;
    int nt = grp >> 2;
    int kbase = kk * 32 + ((lane >> 4) << 3);
    int c = nt * 16 + (lane & 15);
#pragma unroll
    for (int j = 0; j < 8; ++j) {
      float v = W1[(kbase + j) * DD + c];
      _Float16 h = (_Float16)v;
      w1hi[t * 8 + j] = h;
      w1lo[t * 8 + j] = (_Float16)(v - (float)h);
    }
  } else if (b == 8) {
    int row = tid >> 1, cc = tid & 1;
    float s = 0.f;
#pragma unroll 8
    for (int c = 0; c < DD; ++c) s += W2[row * DD + c] * Wc[c * 2 + cc];
    w2c[row * 2 + cc] = s;
    if (tid < 2) {
      float bb = 0.f;
      for (int c = 0; c < DD; ++c) bb += b2[c] * Wc[c * 2 + tid];
      zc[tid] = bb + bc[tid];
    }
  } else {
    int w = tid >> 6;
    int i0 = (b - 9) * CH4;
    int i1 = i0 + CH4; if (i1 > NI4) i1 = NI4;
    if (tid < NSB) {
#pragma unroll
      for (int ww = 0; ww < 4; ++ww) { cntd[ww][tid] = 0; cnts[ww][tid] = 0; }
    }
    __syncthreads();
    const v4i* s4 = (const v4i*)src;
    const v4i* d4 = (const v4i*)dst;
    for (int i = i0 + tid; i < i1; i += 256) {
      v4i sv = __builtin_nontemporal_load(&s4[i]);
      v4i dv = __builtin_nontemporal_load(&d4[i]);
#pragma unroll
      for (int k = 0; k < 4; ++k) {
        atomicAdd(&cntd[w][dv[k] / SUBN], 1);
        atomicAdd(&cnts[w][sv[k] / SUBN], 1);
      }
    }
    __syncthreads();
    if (tid < NSB) {
      int run = 0;
#pragma unroll
      for (int ww = 0; ww < 4; ++ww) { wbd[ww][tid] = run; run += cntd[ww][tid]; }
      based[tid] = atomicAdd(&cur_d[tid], run);
#pragma unroll
      for (int ww = 0; ww < 4; ++ww) cntd[ww][tid] = 0;
    } else if (tid < 2 * NSB) {
      int q = tid - NSB;
      int run = 0;
#pragma unroll
      for (int ww = 0; ww < 4; ++ww) { wbs[ww][q] = run; run += cnts[ww][q]; }
      bases[q] = atomicAdd(&cur_s[q], run);
#pragma unroll
      for (int ww = 0; ww < 4; ++ww) cnts[ww][q] = 0;
    }
    __syncthreads();
    for (int i = i0 + tid; i < i1; i += 256) {
      v4i sv = __builtin_nontemporal_load(&s4[i]);
      v4i dv = __builtin_nontemporal_load(&d4[i]);
#pragma unroll
      for (int k = 0; k < 4; ++k) {
        int d = dv[k], s = sv[k];
        int bd = d / SUBN;
        int pd = based[bd] + wbd[w][bd] + atomicAdd(&cntd[w][bd], 1);
        if (pd < SBCAP) byDst[(size_t)bd * SBCAP + pd] = ((unsigned long long)(unsigned)d << 32) | (unsigned)s;
        int bs = s / SUBN;
        int ps = bases[bs] + wbs[w][bs] + atomicAdd(&cnts[w][bs], 1);
        if (ps < SBCAP) bySrc[(size_t)bs * SBCAP + ps] = (unsigned short)(s - bs * SUBN);
      }
    }
  }
}

// ---- merged P2: blocks 0-63 dst-side (CSR + deg_in + in_norm),
//                 blocks 64-127 src-side (out_norm). No global atomics. ----
__global__ __launch_bounds__(1024) void k_csr2(
    const unsigned long long* __restrict__ byDst, const int* __restrict__ cur_d,
    const unsigned short* __restrict__ bySrc, const int* __restrict__ cur_s,
    int* __restrict__ csr, int* __restrict__ row_start, int* __restrict__ deg_in,
    float* __restrict__ in_norm, float* __restrict__ out_norm) {
  __shared__ int hist[SUBN];
  __shared__ int wsum[16];
  int b = blockIdx.x;
  int tid = threadIdx.x;
  if (b < 64) {
    int q = b;
    int nlo = q * SUBN;
    int nhi = nlo + SUBN; if (nhi > NN) nhi = NN;
    int nloc = nhi - nlo;
    for (int i = tid; i < SUBN; i += 1024) hist[i] = 0;
    __syncthreads();
    int m = cur_d[q];
    if (m > SBCAP) m = SBCAP;
    const unsigned long long* bine = byDst + (size_t)q * SBCAP;
    for (int i = tid; i < m; i += 1024) {
      int l = (int)(bine[i] >> 32) - nlo;
      if (l >= 0 && l < nloc) atomicAdd(&hist[l], 1);
    }
    __syncthreads();
    int v = (tid < SUBN) ? hist[tid] : 0;
    int incl = v;
    int lane = tid & 63;
#pragma unroll
    for (int off = 1; off < 64; off <<= 1) {
      int t2 = __shfl_up(incl, off);
      if (lane >= off) incl += t2;
    }
    int wid = tid >> 6;
    if (lane == 63) wsum[wid] = incl;
    __syncthreads();
    if (tid == 0) {
      int run = 0;
      for (int i = 0; i < 16; ++i) { int t = wsum[i]; wsum[i] = run; run += t; }
    }
    __syncthreads();
    int excl = incl - v + wsum[wid];
    if (tid < nloc) {
      deg_in[nlo + tid] = v;
      row_start[nlo + tid] = q * SBCAP + excl;
      in_norm[nlo + tid] = v > 0 ? rsqrtf((float)v) : 0.f;
    }
    __syncthreads();
    if (tid < SUBN) hist[tid] = excl;   // scatter cursor
    __syncthreads();
    for (int i = tid; i < m; i += 1024) {
      unsigned long long p = bine[i];
      int l = (int)(p >> 32) - nlo;
      if (l >= 0 && l < nloc) {
        int pos = atomicAdd(&hist[l], 1);
        if (pos < SBCAP) csr[(size_t)q * SBCAP + pos] = (int)(unsigned)p;
      }
    }
  } else {
    int q = b - 64;
    int nlo = q * SUBN;
    int nhi = nlo + SUBN; if (nhi > NN) nhi = NN;
    int nloc = nhi - nlo;
    for (int i = tid; i < SUBN; i += 1024) hist[i] = 0;
    __syncthreads();
    int m = cur_s[q];
    if (m > SBCAP) m = SBCAP;
    const unsigned short* bine = bySrc + (size_t)q * SBCAP;
    for (int i = tid; i < m; i += 1024) {
      atomicAdd(&hist[bine[i]], 1);
    }
    __syncthreads();
    for (int i = tid; i < nloc; i += 1024) {
      int od = hist[i];
      out_norm[nlo + i] = od > 0 ? rsqrtf((float)od) : 0.f;
    }
  }
}

// ---- aggregation (layer 1): HALF-WAVE per node. Lanes 0-31 own node A,
// lanes 32-63 own node B (width-32 shfl broadcasts). Each half gathers full
// 256 B rows at 8 B/lane; 8-deep unroll -> 16 rows in flight per wave.
// No guards in unrolled body, no cross-lane reduce (lane owns its 4 cols). ----
__global__ __launch_bounds__(256) void k_agg(
    const __half* __restrict__ x, const int* __restrict__ csr,
    const int* __restrict__ row_start, const int* __restrict__ deg_in,
    const float* __restrict__ out_norm, uint2* __restrict__ agg) {
  int tid = threadIdx.x;
  int wid = tid >> 6;
  int lane = tid & 63;
  int l32 = lane & 31;
  int node = blockIdx.x * 8 + wid * 2 + (lane >> 5);
  bool valid = node < NN;
  int n = valid ? deg_in[node] : 0;
  const int* bk = csr + (valid ? row_start[node] : 0);
  const uint2* xv = (const uint2*)x;   // 8 B slots; row = 32 slots
  float4 a0 = {0.f,0.f,0.f,0.f}, a1 = {0.f,0.f,0.f,0.f};
  float4 a2 = {0.f,0.f,0.f,0.f}, a3 = {0.f,0.f,0.f,0.f};
  for (int c0 = 0; c0 < n; c0 += 32) {
    int nn = n - c0; if (nn > 32) nn = 32;
    int sl = 0; float wl = 0.f;
    if (l32 < nn) { sl = bk[c0 + l32]; wl = out_norm[sl]; }
    int j = 0;
    for (; j + 8 <= nn; j += 8) {
      int s0 = __shfl(sl, j + 0, 32), s1 = __shfl(sl, j + 1, 32);
      int s2 = __shfl(sl, j + 2, 32), s3 = __shfl(sl, j + 3, 32);
      int s4 = __shfl(sl, j + 4, 32), s5 = __shfl(sl, j + 5, 32);
      int s6 = __shfl(sl, j + 6, 32), s7 = __shfl(sl, j + 7, 32);
      float w0 = __shfl(wl, j + 0, 32), w1 = __shfl(wl, j + 1, 32);
      float w2 = __shfl(wl, j + 2, 32), w3 = __shfl(wl, j + 3, 32);
      float w4 = __shfl(wl, j + 4, 32), w5 = __shfl(wl, j + 5, 32);
      float w6 = __shfl(wl, j + 6, 32), w7 = __shfl(wl, j + 7, 32);
      uint2 r0 = xv[(size_t)s0 * 32 + l32];
      uint2 r1 = xv[(size_t)s1 * 32 + l32];
      uint2 r2 = xv[(size_t)s2 * 32 + l32];
      uint2 r3 = xv[(size_t)s3 * 32 + l32];
      uint2 r4 = xv[(size_t)s4 * 32 + l32];
      uint2 r5 = xv[(size_t)s5 * 32 + l32];
      uint2 r6 = xv[(size_t)s6 * 32 + l32];
      uint2 r7 = xv[(size_t)s7 * 32 + l32];
      float2 f;
      f = __half22float2(*(__half2*)&r0.x); a0.x += f.x * w0; a0.y += f.y * w0;
      f = __half22float2(*(__half2*)&r0.y); a0.z += f.x * w0; a0.w += f.y * w0;
      f = __half22float2(*(__half2*)&r1.x); a1.x += f.x * w1; a1.y += f.y * w1;
      f = __half22float2(*(__half2*)&r1.y); a1.z += f.x * w1; a1.w += f.y * w1;
      f = __half22float2(*(__half2*)&r2.x); a2.x += f.x * w2; a2.y += f.y * w2;
      f = __half22float2(*(__half2*)&r2.y); a2.z += f.x * w2; a2.w += f.y * w2;
      f = __half22float2(*(__half2*)&r3.x); a3.x += f.x * w3; a3.y += f.y * w3;
      f = __half22float2(*(__half2*)&r3.y); a3.z += f.x * w3; a3.w += f.y * w3;
      f = __half22float2(*(__half2*)&r4.x); a0.x += f.x * w4; a0.y += f.y * w4;
      f = __half22float2(*(__half2*)&r4.y); a0.z += f.x * w4; a0.w += f.y * w4;
      f = __half22float2(*(__half2*)&r5.x); a1.x += f.x * w5; a1.y += f.y * w5;
      f = __half22float2(*(__half2*)&r5.y); a1.z += f.x * w5; a1.w += f.y * w5;
      f = __half22float2(*(__half2*)&r6.x); a2.x += f.x * w6; a2.y += f.y * w6;
      f = __half22float2(*(__half2*)&r6.y); a2.z += f.x * w6; a2.w += f.y * w6;
      f = __half22float2(*(__half2*)&r7.x); a3.x += f.x * w7; a3.y += f.y * w7;
      f = __half22float2(*(__half2*)&r7.y); a3.z += f.x * w7; a3.w += f.y * w7;
    }
    for (; j < nn; ++j) {
      int s = __shfl(sl, j, 32);
      float w = __shfl(wl, j, 32);
      uint2 r = xv[(size_t)s * 32 + l32];
      float2 f;
      f = __half22float2(*(__half2*)&r.x); a0.x += f.x * w; a0.y += f.y * w;
      f = __half22float2(*(__half2*)&r.y); a0.z += f.x * w; a0.w += f.y * w;
    }
  }
  a0.x += a1.x + a2.x + a3.x;
  a0.y += a1.y + a2.y + a3.y;
  a0.z += a1.z + a2.z + a3.z;
  a0.w += a1.w + a2.w + a3.w;
  if (valid) {
    __half2 h0 = __floats2half2_rn(a0.x, a0.y);
    __half2 h1 = __floats2half2_rn(a0.z, a0.w);
    uint2 o;
    o.x = *(unsigned int*)&h0;
    o.y = *(unsigned int*)&h1;
    agg[(size_t)node * 32 + l32] = o;
  }
}

// ---- layer-1 MFMA GEMM + fused layer-2 projection ----
__global__ __launch_bounds__(256, 4) void k_gemm1(
    const __half* __restrict__ A, const float* __restrict__ in_norm,
    const float* __restrict__ out_norm,
    const _Float16* __restrict__ Whi, const _Float16* __restrict__ Wlo,
    const float* __restrict__ bias, const float* __restrict__ W2c,
    float2* __restrict__ p) {
  int tid = threadIdx.x;
  int wid = tid >> 6, lane = tid & 63;
  int row0 = blockIdx.x * 64 + wid * 16;
  int ar = row0 + (lane & 15);
  bool rv = ar < NN;
  f16x8 a_[4];
#pragma unroll
  for (int kk = 0; kk < 4; ++kk) {
    if (rv) {
      a_[kk] = *(const f16x8*)((const _Float16*)A + (size_t)ar * DD + kk * 32 + ((lane >> 4) << 3));
    } else {
      a_[kk] = (f16x8){0, 0, 0, 0, 0, 0, 0, 0};
    }
  }
  f32x4 acc[8];
#pragma unroll
  for (int nt = 0; nt < 8; ++nt) acc[nt] = (f32x4){0.f, 0.f, 0.f, 0.f};
#pragma unroll
  for (int nt = 0; nt < 8; ++nt) {
#pragma unroll
    for (int kk = 0; kk < 4; ++kk) {
      f16x8 bh = *(const f16x8*)&Whi[(((nt * 4 + kk) * 64) + lane) * 8];
      f16x8 bl = *(const f16x8*)&Wlo[(((nt * 4 + kk) * 64) + lane) * 8];
      acc[nt] = __builtin_amdgcn_mfma_f32_16x16x32_f16(a_[kk], bh, acc[nt], 0, 0, 0);
      acc[nt] = __builtin_amdgcn_mfma_f32_16x16x32_f16(a_[kk], bl, acc[nt], 0, 0, 0);
    }
  }
  int r4 = (lane >> 4) * 4;
  int c0 = lane & 15;
  float wc0[8], wc1[8], bv[8];
#pragma unroll
  for (int nt = 0; nt < 8; ++nt) {
    int col = nt * 16 + c0;
    wc0[nt] = W2c[col * 2 + 0];
    wc1[nt] = W2c[col * 2 + 1];
    bv[nt] = bias[col];
  }
#pragma unroll
  for (int reg = 0; reg < 4; ++reg) {
    int row = row0 + r4 + reg;
    float inm = (row < NN) ? in_norm[row] : 0.f;
    float v0 = 0.f, v1 = 0.f;
#pragma unroll
    for (int nt = 0; nt < 8; ++nt) {
      float y = acc[nt][reg] * inm + bv[nt];
      y = fmaxf(y, 0.f);
      v0 += y * wc0[nt];
      v1 += y * wc1[nt];
    }
#pragma unroll
    for (int off = 1; off < 16; off <<= 1) {
      v0 += __shfl_xor(v0, off);
      v1 += __shfl_xor(v1, off);
    }
    if (row < NN && c0 == 0) {
      float onm = out_norm[row];
      p[row] = make_float2(v0 * onm, v1 * onm);
    }
  }
}

// ---- layer-2 aggregation on 2-dim projections ----
__global__ __launch_bounds__(256) void k_agg2(
    const float2* __restrict__ p, const int* __restrict__ csr,
    const int* __restrict__ row_start, const int* __restrict__ deg_in,
    const float* __restrict__ in_norm, float2* __restrict__ z) {
  int i = blockIdx.x * 256 + threadIdx.x;
  if (i >= NN) return;
  int n = deg_in[i];
  const int* bk = csr + row_start[i];
  float2 s0 = {0.f, 0.f}, s1 = {0.f, 0.f}, s2 = {0.f, 0.f}, s3 = {0.f, 0.f};
  int j = 0;
  for (; j + 4 <= n; j += 4) {
    int i0 = bk[j], i1 = bk[j + 1], i2 = bk[j + 2], i3 = bk[j + 3];
    float2 q0 = p[i0], q1 = p[i1], q2 = p[i2], q3 = p[i3];
    s0.x += q0.x; s0.y += q0.y;
    s1.x += q1.x; s1.y += q1.y;
    s2.x += q2.x; s2.y += q2.y;
    s3.x += q3.x; s3.y += q3.y;
  }
  for (; j < n; ++j) {
    float2 q = p[bk[j]];
    s0.x += q.x; s0.y += q.y;
  }
  s0.x += s1.x + s2.x + s3.x;
  s0.y += s1.y + s2.y + s3.y;
  float inm = in_norm[i];
  z[i] = make_float2(s0.x * inm, s0.y * inm);
}

// ---- pool: one wave per graph; segment-mean of z + zc -> out ----
__global__ __launch_bounds__(256) void k_pool2(
    const float* __restrict__ z, const int* __restrict__ gid,
    const float* __restrict__ zc, float* __restrict__ out) {
  int g = blockIdx.x * 4 + (threadIdx.x >> 6);
  int lane = threadIdx.x & 63;
  if (g >= NG) return;
  int lo, hi;
  { int a = 0, b = NN; while (a < b) { int m = (a + b) >> 1; if (gid[m] < g) a = m + 1; else b = m; } lo = a; }
  { int a = lo, b = NN; while (a < b) { int m = (a + b) >> 1; if (gid[m] <= g) a = m + 1; else b = m; } hi = a; }
  float s = 0.f;
  int col = lane & 1;
  for (int i = lo + (lane >> 1); i < hi; i += 32) s += z[i * 2 + col];
#pragma unroll
  for (int off = 32; off >= 2; off >>= 1) s += __shfl_down(s, off);
  if (lane < 2) {
    int n = hi - lo;
    out[g * 2 + lane] = s / (float)(n > 0 ? n : 1) + zc[lane];
  }
}

extern "C" void kernel_launch(void* const* d_in, const int* in_sizes, int n_in,
                              void* d_out, int out_size, void* d_ws, size_t ws_size,
                              hipStream_t stream) {
  const float* features = (const float*)d_in[0];
  const int* src = (const int*)d_in[1];
  const int* dst = (const int*)d_in[2];
  const int* gid = (const int*)d_in[3];
  const float* W1 = (const float*)d_in[4];
  const float* b1 = (const float*)d_in[5];
  const float* W2 = (const float*)d_in[6];
  const float* b2 = (const float*)d_in[7];
  const float* Wc = (const float*)d_in[8];
  const float* bc = (const float*)d_in[9];
  float* out = (float*)d_out;

  char* ws = (char*)d_ws;
  size_t off = 0;
  auto take = [&](size_t bytes) {
    char* p = ws + off;
    off = (off + bytes + 255) & ~(size_t)255;
    return p;
  };
  int* cur_d      = (int*)take(NSB * 4);   // cur_d at +0, cur_s at +256 B
  int* cur_s      = (int*)take(NSB * 4);
  int* deg_in     = (int*)take((size_t)NN * 4);
  float* out_nrm  = (float*)take((size_t)NN * 4);
  float* in_nrm   = (float*)take((size_t)NN * 4);
  int* row_start  = (int*)take((size_t)NN * 4);
  float* pbuf     = (float*)take((size_t)NN * 2 * 4);
  float* zbuf     = (float*)take((size_t)NN * 2 * 4);
  float* w2c      = (float*)take((size_t)DD * 2 * 4);
  float* zc       = (float*)take(2 * 4);
  unsigned long long* byDst = (unsigned long long*)take((size_t)NSB * SBCAP * 8);
  unsigned short* bySrc = (unsigned short*)take((size_t)NSB * SBCAP * 2);
  int* csr        = (int*)take((size_t)NSB * SBCAP * 4);
  __half* xh      = (__half*)take((size_t)NN * DD * 2);
  __half* bufA    = (__half*)take((size_t)NN * DD * 2);
  _Float16* w1hi  = (_Float16*)take((size_t)DD * DD * 2);
  _Float16* w1lo  = (_Float16*)take((size_t)DD * DD * 2);

  // zero bin cursors
  k_zero<<<1, 128, 0, stream>>>(cur_d);

  // prep: W1 split + W2c + edge binning + f2h
  k_prep<<<521 + F2HB, 256, 0, stream>>>(
      W1, W2, Wc, b2, bc, w1hi, w1lo, w2c, zc,
      src, dst, cur_d, cur_s, byDst, bySrc,
      (const float4*)features, (uint2*)xh);

  // CSR build + degrees + norms
  k_csr2<<<128, 1024, 0, stream>>>(
      byDst, cur_d, bySrc, cur_s, csr, row_start, deg_in, in_nrm, out_nrm);

  // layer 1: agg (half-wave per node, 16 rows in flight) -> bufA ; GEMM -> pbuf
  k_agg<<<(NN + 7) / 8, 256, 0, stream>>>(
      xh, csr, row_start, deg_in, out_nrm, (uint2*)bufA);
  k_gemm1<<<(NN + 63) / 64, 256, 0, stream>>>(
      bufA, in_nrm, out_nrm, w1hi, w1lo, b1, w2c, (float2*)pbuf);

  // layer 2 (algebraically reduced): 2-dim aggregate + norm -> zbuf
  k_agg2<<<(NN + 255) / 256, 256, 0, stream>>>(
      (const float2*)pbuf, csr, row_start, deg_in, in_nrm, (float2*)zbuf);

  // segment mean-pool (+ b2@Wc + bc)
  k_pool2<<<(NG + 3) / 4, 256, 0, stream>>>(zbuf, gid, zc, out);
}

// Round 21
// 106.869 us; speedup vs baseline: 1.1442x; 1.0342x over previous
//
#include <hip/hip_runtime.h>
#include <hip/hip_fp16.h>

#define NN 50000
#define NE 800000
#define NG 512
#define DD 128
#define NSB 64               // sub-bins == subpartitions
#define SUBN 782             // ceil(NN/NSB)
#define SBCAP 14336          // per-sub-bin capacity
#define NB1 512
#define NI4 (NE / 4)
#define CH4 ((NI4 + NB1 - 1) / NB1)
#define F2HB 6250            // f2h blocks: NN*32/256

typedef __attribute__((ext_vector_type(8))) _Float16 f16x8;
typedef __attribute__((ext_vector_type(4))) float f32x4;
typedef int v4i __attribute__((ext_vector_type(4)));

// ---- zero the bin cursors ----
__global__ void k_zero(int* __restrict__ p) {
  p[threadIdx.x] = 0;   // 128 ints: cur_d[64] + cur_s[64]
}

// ---- merged prep: b<8 W1-split | b==8 W2c | 9<=b<521 edge binning | b>=521 f2h ----
// byDst entries packed u32: (dst_local_id << 16) | src_global_id  (both < 2^16).
__global__ __launch_bounds__(256) void k_prep(
    const float* __restrict__ W1, const float* __restrict__ W2,
    const float* __restrict__ Wc, const float* __restrict__ b2,
    const float* __restrict__ bc,
    _Float16* __restrict__ w1hi, _Float16* __restrict__ w1lo,
    float* __restrict__ w2c, float* __restrict__ zc,
    const int* __restrict__ src, const int* __restrict__ dst,
    int* __restrict__ cur_d, int* __restrict__ cur_s,
    unsigned int* __restrict__ byDst, unsigned short* __restrict__ bySrc,
    const float4* __restrict__ x, uint2* __restrict__ xh) {
  __shared__ int cntd[4][NSB], cnts[4][NSB], based[NSB], bases[NSB];
  __shared__ int wbd[4][NSB], wbs[4][NSB];
  int b = blockIdx.x;
  int tid = threadIdx.x;
  if (b >= 521) {
    int i = (b - 521) * 256 + tid;      // < NN*32
    float4 v = x[i];
    __half2 a = __floats2half2_rn(v.x, v.y);
    __half2 c = __floats2half2_rn(v.z, v.w);
    uint2 o;
    o.x = *(unsigned int*)&a;
    o.y = *(unsigned int*)&c;
    xh[i] = o;
  } else if (b < 8) {
    int t = b * 256 + tid;
    int lane = t & 63;
    int grp = t >> 6;
    int kk = grp & 3;
    int nt = grp >> 2;
    int kbase = kk * 32 + ((lane >> 4) << 3);
    int c = nt * 16 + (lane & 15);
#pragma unroll
    for (int j = 0; j < 8; ++j) {
      float v = W1[(kbase + j) * DD + c];
      _Float16 h = (_Float16)v;
      w1hi[t * 8 + j] = h;
      w1lo[t * 8 + j] = (_Float16)(v - (float)h);
    }
  } else if (b == 8) {
    int row = tid >> 1, cc = tid & 1;
    float s = 0.f;
#pragma unroll 8
    for (int c = 0; c < DD; ++c) s += W2[row * DD + c] * Wc[c * 2 + cc];
    w2c[row * 2 + cc] = s;
    if (tid < 2) {
      float bb = 0.f;
      for (int c = 0; c < DD; ++c) bb += b2[c] * Wc[c * 2 + tid];
      zc[tid] = bb + bc[tid];
    }
  } else {
    int w = tid >> 6;
    int i0 = (b - 9) * CH4;
    int i1 = i0 + CH4; if (i1 > NI4) i1 = NI4;
    if (tid < NSB) {
#pragma unroll
      for (int ww = 0; ww < 4; ++ww) { cntd[ww][tid] = 0; cnts[ww][tid] = 0; }
    }
    __syncthreads();
    const v4i* s4 = (const v4i*)src;
    const v4i* d4 = (const v4i*)dst;
    for (int i = i0 + tid; i < i1; i += 256) {
      v4i sv = __builtin_nontemporal_load(&s4[i]);
      v4i dv = __builtin_nontemporal_load(&d4[i]);
#pragma unroll
      for (int k = 0; k < 4; ++k) {
        atomicAdd(&cntd[w][dv[k] / SUBN], 1);
        atomicAdd(&cnts[w][sv[k] / SUBN], 1);
      }
    }
    __syncthreads();
    if (tid < NSB) {
      int run = 0;
#pragma unroll
      for (int ww = 0; ww < 4; ++ww) { wbd[ww][tid] = run; run += cntd[ww][tid]; }
      based[tid] = atomicAdd(&cur_d[tid], run);
#pragma unroll
      for (int ww = 0; ww < 4; ++ww) cntd[ww][tid] = 0;
    } else if (tid < 2 * NSB) {
      int q = tid - NSB;
      int run = 0;
#pragma unroll
      for (int ww = 0; ww < 4; ++ww) { wbs[ww][q] = run; run += cnts[ww][q]; }
      bases[q] = atomicAdd(&cur_s[q], run);
#pragma unroll
      for (int ww = 0; ww < 4; ++ww) cnts[ww][q] = 0;
    }
    __syncthreads();
    for (int i = i0 + tid; i < i1; i += 256) {
      v4i sv = __builtin_nontemporal_load(&s4[i]);
      v4i dv = __builtin_nontemporal_load(&d4[i]);
#pragma unroll
      for (int k = 0; k < 4; ++k) {
        int d = dv[k], s = sv[k];
        int bd = d / SUBN;
        int dloc = d - bd * SUBN;
        int pd = based[bd] + wbd[w][bd] + atomicAdd(&cntd[w][bd], 1);
        if (pd < SBCAP)
          byDst[(size_t)bd * SBCAP + pd] = ((unsigned)dloc << 16) | (unsigned)s;
        int bs = s / SUBN;
        int ps = bases[bs] + wbs[w][bs] + atomicAdd(&cnts[w][bs], 1);
        if (ps < SBCAP) bySrc[(size_t)bs * SBCAP + ps] = (unsigned short)(s - bs * SUBN);
      }
    }
  }
}

// ---- merged P2: blocks 0-63 dst-side (u16 CSR + deg_in + in_norm),
//                 blocks 64-127 src-side (out_norm). No global atomics. ----
__global__ __launch_bounds__(1024) void k_csr2(
    const unsigned int* __restrict__ byDst, const int* __restrict__ cur_d,
    const unsigned short* __restrict__ bySrc, const int* __restrict__ cur_s,
    unsigned short* __restrict__ csr, int* __restrict__ row_start,
    int* __restrict__ deg_in,
    float* __restrict__ in_norm, float* __restrict__ out_norm) {
  __shared__ int hist[SUBN];
  __shared__ int wsum[16];
  int b = blockIdx.x;
  int tid = threadIdx.x;
  if (b < 64) {
    int q = b;
    int nlo = q * SUBN;
    int nhi = nlo + SUBN; if (nhi > NN) nhi = NN;
    int nloc = nhi - nlo;
    for (int i = tid; i < SUBN; i += 1024) hist[i] = 0;
    __syncthreads();
    int m = cur_d[q];
    if (m > SBCAP) m = SBCAP;
    const unsigned int* bine = byDst + (size_t)q * SBCAP;
    for (int i = tid; i < m; i += 1024) {
      int l = (int)(bine[i] >> 16);
      if (l < nloc) atomicAdd(&hist[l], 1);
    }
    __syncthreads();
    int v = (tid < SUBN) ? hist[tid] : 0;
    int incl = v;
    int lane = tid & 63;
#pragma unroll
    for (int off = 1; off < 64; off <<= 1) {
      int t2 = __shfl_up(incl, off);
      if (lane >= off) incl += t2;
    }
    int wid = tid >> 6;
    if (lane == 63) wsum[wid] = incl;
    __syncthreads();
    if (tid == 0) {
      int run = 0;
      for (int i = 0; i < 16; ++i) { int t = wsum[i]; wsum[i] = run; run += t; }
    }
    __syncthreads();
    int excl = incl - v + wsum[wid];
    if (tid < nloc) {
      deg_in[nlo + tid] = v;
      row_start[nlo + tid] = q * SBCAP + excl;
      in_norm[nlo + tid] = v > 0 ? rsqrtf((float)v) : 0.f;
    }
    __syncthreads();
    if (tid < SUBN) hist[tid] = excl;   // scatter cursor
    __syncthreads();
    for (int i = tid; i < m; i += 1024) {
      unsigned int p = bine[i];
      int l = (int)(p >> 16);
      if (l < nloc) {
        int pos = atomicAdd(&hist[l], 1);
        if (pos < SBCAP) csr[(size_t)q * SBCAP + pos] = (unsigned short)(p & 0xFFFFu);
      }
    }
  } else {
    int q = b - 64;
    int nlo = q * SUBN;
    int nhi = nlo + SUBN; if (nhi > NN) nhi = NN;
    int nloc = nhi - nlo;
    for (int i = tid; i < SUBN; i += 1024) hist[i] = 0;
    __syncthreads();
    int m = cur_s[q];
    if (m > SBCAP) m = SBCAP;
    const unsigned short* bine = bySrc + (size_t)q * SBCAP;
    for (int i = tid; i < m; i += 1024) {
      atomicAdd(&hist[bine[i]], 1);
    }
    __syncthreads();
    for (int i = tid; i < nloc; i += 1024) {
      int od = hist[i];
      out_norm[nlo + i] = od > 0 ? rsqrtf((float)od) : 0.f;
    }
  }
}

// ---- aggregation (layer 1): HALF-WAVE per node, u16 edge ids.
// Lanes 0-31 own node A, 32-63 node B (width-32 shfl). 8 B/lane row gathers,
// 8-deep unroll -> 16 rows in flight per wave. ----
__global__ __launch_bounds__(256) void k_agg(
    const __half* __restrict__ x, const unsigned short* __restrict__ csr,
    const int* __restrict__ row_start, const int* __restrict__ deg_in,
    const float* __restrict__ out_norm, uint2* __restrict__ agg) {
  int tid = threadIdx.x;
  int wid = tid >> 6;
  int lane = tid & 63;
  int l32 = lane & 31;
  int node = blockIdx.x * 8 + wid * 2 + (lane >> 5);
  bool valid = node < NN;
  int n = valid ? deg_in[node] : 0;
  const unsigned short* bk = csr + (valid ? row_start[node] : 0);
  const uint2* xv = (const uint2*)x;   // 8 B slots; row = 32 slots
  float4 a0 = {0.f,0.f,0.f,0.f}, a1 = {0.f,0.f,0.f,0.f};
  float4 a2 = {0.f,0.f,0.f,0.f}, a3 = {0.f,0.f,0.f,0.f};
  for (int c0 = 0; c0 < n; c0 += 32) {
    int nn = n - c0; if (nn > 32) nn = 32;
    int sl = 0; float wl = 0.f;
    if (l32 < nn) { sl = (int)bk[c0 + l32]; wl = out_norm[sl]; }
    int j = 0;
    for (; j + 8 <= nn; j += 8) {
      int s0 = __shfl(sl, j + 0, 32), s1 = __shfl(sl, j + 1, 32);
      int s2 = __shfl(sl, j + 2, 32), s3 = __shfl(sl, j + 3, 32);
      int s4 = __shfl(sl, j + 4, 32), s5 = __shfl(sl, j + 5, 32);
      int s6 = __shfl(sl, j + 6, 32), s7 = __shfl(sl, j + 7, 32);
      float w0 = __shfl(wl, j + 0, 32), w1 = __shfl(wl, j + 1, 32);
      float w2 = __shfl(wl, j + 2, 32), w3 = __shfl(wl, j + 3, 32);
      float w4 = __shfl(wl, j + 4, 32), w5 = __shfl(wl, j + 5, 32);
      float w6 = __shfl(wl, j + 6, 32), w7 = __shfl(wl, j + 7, 32);
      uint2 r0 = xv[(size_t)s0 * 32 + l32];
      uint2 r1 = xv[(size_t)s1 * 32 + l32];
      uint2 r2 = xv[(size_t)s2 * 32 + l32];
      uint2 r3 = xv[(size_t)s3 * 32 + l32];
      uint2 r4 = xv[(size_t)s4 * 32 + l32];
      uint2 r5 = xv[(size_t)s5 * 32 + l32];
      uint2 r6 = xv[(size_t)s6 * 32 + l32];
      uint2 r7 = xv[(size_t)s7 * 32 + l32];
      float2 f;
      f = __half22float2(*(__half2*)&r0.x); a0.x += f.x * w0; a0.y += f.y * w0;
      f = __half22float2(*(__half2*)&r0.y); a0.z += f.x * w0; a0.w += f.y * w0;
      f = __half22float2(*(__half2*)&r1.x); a1.x += f.x * w1; a1.y += f.y * w1;
      f = __half22float2(*(__half2*)&r1.y); a1.z += f.x * w1; a1.w += f.y * w1;
      f = __half22float2(*(__half2*)&r2.x); a2.x += f.x * w2; a2.y += f.y * w2;
      f = __half22float2(*(__half2*)&r2.y); a2.z += f.x * w2; a2.w += f.y * w2;
      f = __half22float2(*(__half2*)&r3.x); a3.x += f.x * w3; a3.y += f.y * w3;
      f = __half22float2(*(__half2*)&r3.y); a3.z += f.x * w3; a3.w += f.y * w3;
      f = __half22float2(*(__half2*)&r4.x); a0.x += f.x * w4; a0.y += f.y * w4;
      f = __half22float2(*(__half2*)&r4.y); a0.z += f.x * w4; a0.w += f.y * w4;
      f = __half22float2(*(__half2*)&r5.x); a1.x += f.x * w5; a1.y += f.y * w5;
      f = __half22float2(*(__half2*)&r5.y); a1.z += f.x * w5; a1.w += f.y * w5;
      f = __half22float2(*(__half2*)&r6.x); a2.x += f.x * w6; a2.y += f.y * w6;
      f = __half22float2(*(__half2*)&r6.y); a2.z += f.x * w6; a2.w += f.y * w6;
      f = __half22float2(*(__half2*)&r7.x); a3.x += f.x * w7; a3.y += f.y * w7;
      f = __half22float2(*(__half2*)&r7.y); a3.z += f.x * w7; a3.w += f.y * w7;
    }
    for (; j < nn; ++j) {
      int s = __shfl(sl, j, 32);
      float w = __shfl(wl, j, 32);
      uint2 r = xv[(size_t)s * 32 + l32];
      float2 f;
      f = __half22float2(*(__half2*)&r.x); a0.x += f.x * w; a0.y += f.y * w;
      f = __half22float2(*(__half2*)&r.y); a0.z += f.x * w; a0.w += f.y * w;
    }
  }
  a0.x += a1.x + a2.x + a3.x;
  a0.y += a1.y + a2.y + a3.y;
  a0.z += a1.z + a2.z + a3.z;
  a0.w += a1.w + a2.w + a3.w;
  if (valid) {
    __half2 h0 = __floats2half2_rn(a0.x, a0.y);
    __half2 h1 = __floats2half2_rn(a0.z, a0.w);
    uint2 o;
    o.x = *(unsigned int*)&h0;
    o.y = *(unsigned int*)&h1;
    agg[(size_t)node * 32 + l32] = o;
  }
}

// ---- layer-1 MFMA GEMM + fused layer-2 projection ----
__global__ __launch_bounds__(256, 4) void k_gemm1(
    const __half* __restrict__ A, const float* __restrict__ in_norm,
    const float* __restrict__ out_norm,
    const _Float16* __restrict__ Whi, const _Float16* __restrict__ Wlo,
    const float* __restrict__ bias, const float* __restrict__ W2c,
    float2* __restrict__ p) {
  int tid = threadIdx.x;
  int wid = tid >> 6, lane = tid & 63;
  int row0 = blockIdx.x * 64 + wid * 16;
  int ar = row0 + (lane & 15);
  bool rv = ar < NN;
  f16x8 a_[4];
#pragma unroll
  for (int kk = 0; kk < 4; ++kk) {
    if (rv) {
      a_[kk] = *(const f16x8*)((const _Float16*)A + (size_t)ar * DD + kk * 32 + ((lane >> 4) << 3));
    } else {
      a_[kk] = (f16x8){0, 0, 0, 0, 0, 0, 0, 0};
    }
  }
  f32x4 acc[8];
#pragma unroll
  for (int nt = 0; nt < 8; ++nt) acc[nt] = (f32x4){0.f, 0.f, 0.f, 0.f};
#pragma unroll
  for (int nt = 0; nt < 8; ++nt) {
#pragma unroll
    for (int kk = 0; kk < 4; ++kk) {
      f16x8 bh = *(const f16x8*)&Whi[(((nt * 4 + kk) * 64) + lane) * 8];
      f16x8 bl = *(const f16x8*)&Wlo[(((nt * 4 + kk) * 64) + lane) * 8];
      acc[nt] = __builtin_amdgcn_mfma_f32_16x16x32_f16(a_[kk], bh, acc[nt], 0, 0, 0);
      acc[nt] = __builtin_amdgcn_mfma_f32_16x16x32_f16(a_[kk], bl, acc[nt], 0, 0, 0);
    }
  }
  int r4 = (lane >> 4) * 4;
  int c0 = lane & 15;
  float wc0[8], wc1[8], bv[8];
#pragma unroll
  for (int nt = 0; nt < 8; ++nt) {
    int col = nt * 16 + c0;
    wc0[nt] = W2c[col * 2 + 0];
    wc1[nt] = W2c[col * 2 + 1];
    bv[nt] = bias[col];
  }
#pragma unroll
  for (int reg = 0; reg < 4; ++reg) {
    int row = row0 + r4 + reg;
    float inm = (row < NN) ? in_norm[row] : 0.f;
    float v0 = 0.f, v1 = 0.f;
#pragma unroll
    for (int nt = 0; nt < 8; ++nt) {
      float y = acc[nt][reg] * inm + bv[nt];
      y = fmaxf(y, 0.f);
      v0 += y * wc0[nt];
      v1 += y * wc1[nt];
    }
#pragma unroll
    for (int off = 1; off < 16; off <<= 1) {
      v0 += __shfl_xor(v0, off);
      v1 += __shfl_xor(v1, off);
    }
    if (row < NN && c0 == 0) {
      float onm = out_norm[row];
      p[row] = make_float2(v0 * onm, v1 * onm);
    }
  }
}

// ---- layer-2 aggregation on 2-dim projections (u16 edge ids) ----
__global__ __launch_bounds__(256) void k_agg2(
    const float2* __restrict__ p, const unsigned short* __restrict__ csr,
    const int* __restrict__ row_start, const int* __restrict__ deg_in,
    const float* __restrict__ in_norm, float2* __restrict__ z) {
  int i = blockIdx.x * 256 + threadIdx.x;
  if (i >= NN) return;
  int n = deg_in[i];
  const unsigned short* bk = csr + row_start[i];
  float2 s0 = {0.f, 0.f}, s1 = {0.f, 0.f}, s2 = {0.f, 0.f}, s3 = {0.f, 0.f};
  int j = 0;
  for (; j + 4 <= n; j += 4) {
    int i0 = bk[j], i1 = bk[j + 1], i2 = bk[j + 2], i3 = bk[j + 3];
    float2 q0 = p[i0], q1 = p[i1], q2 = p[i2], q3 = p[i3];
    s0.x += q0.x; s0.y += q0.y;
    s1.x += q1.x; s1.y += q1.y;
    s2.x += q2.x; s2.y += q2.y;
    s3.x += q3.x; s3.y += q3.y;
  }
  for (; j < n; ++j) {
    float2 q = p[bk[j]];
    s0.x += q.x; s0.y += q.y;
  }
  s0.x += s1.x + s2.x + s3.x;
  s0.y += s1.y + s2.y + s3.y;
  float inm = in_norm[i];
  z[i] = make_float2(s0.x * inm, s0.y * inm);
}

// ---- pool: one wave per graph; segment-mean of z + zc -> out ----
__global__ __launch_bounds__(256) void k_pool2(
    const float* __restrict__ z, const int* __restrict__ gid,
    const float* __restrict__ zc, float* __restrict__ out) {
  int g = blockIdx.x * 4 + (threadIdx.x >> 6);
  int lane = threadIdx.x & 63;
  if (g >= NG) return;
  int lo, hi;
  { int a = 0, b = NN; while (a < b) { int m = (a + b) >> 1; if (gid[m] < g) a = m + 1; else b = m; } lo = a; }
  { int a = lo, b = NN; while (a < b) { int m = (a + b) >> 1; if (gid[m] <= g) a = m + 1; else b = m; } hi = a; }
  float s = 0.f;
  int col = lane & 1;
  for (int i = lo + (lane >> 1); i < hi; i += 32) s += z[i * 2 + col];
#pragma unroll
  for (int off = 32; off >= 2; off >>= 1) s += __shfl_down(s, off);
  if (lane < 2) {
    int n = hi - lo;
    out[g * 2 + lane] = s / (float)(n > 0 ? n : 1) + zc[lane];
  }
}

extern "C" void kernel_launch(void* const* d_in, const int* in_sizes, int n_in,
                              void* d_out, int out_size, void* d_ws, size_t ws_size,
                              hipStream_t stream) {
  const float* features = (const float*)d_in[0];
  const int* src = (const int*)d_in[1];
  const int* dst = (const int*)d_in[2];
  const int* gid = (const int*)d_in[3];
  const float* W1 = (const float*)d_in[4];
  const float* b1 = (const float*)d_in[5];
  const float* W2 = (const float*)d_in[6];
  const float* b2 = (const float*)d_in[7];
  const float* Wc = (const float*)d_in[8];
  const float* bc = (const float*)d_in[9];
  float* out = (float*)d_out;

  char* ws = (char*)d_ws;
  size_t off = 0;
  auto take = [&](size_t bytes) {
    char* p = ws + off;
    off = (off + bytes + 255) & ~(size_t)255;
    return p;
  };
  int* cur_d      = (int*)take(NSB * 4);   // cur_d at +0, cur_s at +256 B
  int* cur_s      = (int*)take(NSB * 4);
  int* deg_in     = (int*)take((size_t)NN * 4);
  float* out_nrm  = (float*)take((size_t)NN * 4);
  float* in_nrm   = (float*)take((size_t)NN * 4);
  int* row_start  = (int*)take((size_t)NN * 4);
  float* pbuf     = (float*)take((size_t)NN * 2 * 4);
  float* zbuf     = (float*)take((size_t)NN * 2 * 4);
  float* w2c      = (float*)take((size_t)DD * 2 * 4);
  float* zc       = (float*)take(2 * 4);
  unsigned int* byDst = (unsigned int*)take((size_t)NSB * SBCAP * 4);
  unsigned short* bySrc = (unsigned short*)take((size_t)NSB * SBCAP * 2);
  unsigned short* csr = (unsigned short*)take((size_t)NSB * SBCAP * 2);
  __half* xh      = (__half*)take((size_t)NN * DD * 2);
  __half* bufA    = (__half*)take((size_t)NN * DD * 2);
  _Float16* w1hi  = (_Float16*)take((size_t)DD * DD * 2);
  _Float16* w1lo  = (_Float16*)take((size_t)DD * DD * 2);

  // zero bin cursors
  k_zero<<<1, 128, 0, stream>>>(cur_d);

  // prep: W1 split + W2c + edge binning (u32 packed) + f2h
  k_prep<<<521 + F2HB, 256, 0, stream>>>(
      W1, W2, Wc, b2, bc, w1hi, w1lo, w2c, zc,
      src, dst, cur_d, cur_s, byDst, bySrc,
      (const float4*)features, (uint2*)xh);

  // CSR build (u16) + degrees + norms
  k_csr2<<<128, 1024, 0, stream>>>(
      byDst, cur_d, bySrc, cur_s, csr, row_start, deg_in, in_nrm, out_nrm);

  // layer 1: agg (half-wave per node, u16 ids) -> bufA ; GEMM + projection -> pbuf
  k_agg<<<(NN + 7) / 8, 256, 0, stream>>>(
      xh, csr, row_start, deg_in, out_nrm, (uint2*)bufA);
  k_gemm1<<<(NN + 63) / 64, 256, 0, stream>>>(
      bufA, in_nrm, out_nrm, w1hi, w1lo, b1, w2c, (float2*)pbuf);

  // layer 2 (algebraically reduced): 2-dim aggregate + norm -> zbuf
  k_agg2<<<(NN + 255) / 256, 256, 0, stream>>>(
      (const float2*)pbuf, csr, row_start, deg_in, in_nrm, (float2*)zbuf);

  // segment mean-pool (+ b2@Wc + bc)
  k_pool2<<<(NG + 3) / 4, 256, 0, stream>>>(zbuf, gid, zc, out);
}